// Round 7
// baseline (407.989 us; speedup 1.0000x reference)
//
#include <hip/hip_runtime.h>

#define NN 100000
#define NE 1600000
#define NBUCK 782   // ceil(NN/128), bucket = dst >> 7
#define PCHUNK 8192 // edges per k_pairs block
#define HISTB 784   // k_hist grid: ~3 blocks/CU for atomic throughput

struct alignas(8) US4 { unsigned short x, y, z, w; };

__device__ __forceinline__ float bfu(unsigned int hw) { return __uint_as_float(hw << 16); }
__device__ __forceinline__ unsigned short f2bf(float f) {
    unsigned int u = __float_as_uint(f);
    return (unsigned short)((u + 0x7fffu + ((u >> 16) & 1u)) >> 16);
}

// ---------------- build: bucket-ordered packed edges -> per-node CSR ----------------

__global__ __launch_bounds__(256) void k_hist(const int* __restrict__ src,
                                              const int* __restrict__ dst,
                                              int* __restrict__ cnt_out,
                                              int* __restrict__ bucket_cnt) {
    __shared__ int hist[NBUCK];
    int tid = threadIdx.x;
    for (int i = tid; i < NBUCK; i += 256) hist[i] = 0;
    __syncthreads();
    int stride = gridDim.x * 256;
    for (int e = blockIdx.x * 256 + tid; e < NE; e += stride) {
        atomicAdd(&hist[dst[e] >> 7], 1);
        atomicAdd(&cnt_out[src[e]], 1);
    }
    __syncthreads();
    for (int i = tid; i < NBUCK; i += 256)
        if (hist[i]) atomicAdd(&bucket_cnt[i], hist[i]);
}

__global__ __launch_bounds__(1024) void k_bscan(const int* __restrict__ bucket_cnt,
                                                int* __restrict__ bucket_base,
                                                int* __restrict__ bucket_cursor) {
    __shared__ int tmp[1024];
    int t = threadIdx.x;
    int v = (t < NBUCK) ? bucket_cnt[t] : 0;
    tmp[t] = v;
    __syncthreads();
    for (int off = 1; off < 1024; off <<= 1) {
        int u = (t >= off) ? tmp[t - off] : 0;
        __syncthreads();
        tmp[t] += u;
        __syncthreads();
    }
    int excl = tmp[t] - v;
    if (t < NBUCK) {
        bucket_base[t] = excl;
        bucket_cursor[t] = excl;
    }
    if (t == 0) bucket_base[NBUCK] = NE;
}

// LDS-binned scatter: bulk range reservation per (block,bucket), then packed
// (src<<7 | dst&127) words written into per-block contiguous runs.
__global__ __launch_bounds__(256) void k_pairs(const int* __restrict__ src,
                                               const int* __restrict__ dst,
                                               int* __restrict__ bucket_cursor,
                                               int* __restrict__ E2) {
    __shared__ int hist[NBUCK], gbase[NBUCK];
    int tid = threadIdx.x;
    for (int i = tid; i < NBUCK; i += 256) hist[i] = 0;
    __syncthreads();
    int base = blockIdx.x * PCHUNK;
#pragma unroll
    for (int i = 0; i < PCHUNK / 256; ++i) {
        int e = base + i * 256 + tid;
        if (e < NE) atomicAdd(&hist[dst[e] >> 7], 1);
    }
    __syncthreads();
    for (int i = tid; i < NBUCK; i += 256) {
        int h = hist[i];
        if (h) gbase[i] = atomicAdd(&bucket_cursor[i], h);
        hist[i] = 0;
    }
    __syncthreads();
#pragma unroll
    for (int i = 0; i < PCHUNK / 256; ++i) {
        int e = base + i * 256 + tid;
        if (e < NE) {
            int d = dst[e];
            int b = d >> 7;
            int pos = atomicAdd(&hist[b], 1);
            E2[gbase[b] + pos] = (src[e] << 7) | (d & 127);
        }
    }
}

// per-bucket: LDS count+scan+cursor -> row_start, r_in, csr (block-local writes)
__global__ __launch_bounds__(256) void k_bcsr(const int* __restrict__ E2,
                                              const int* __restrict__ bucket_base,
                                              int* __restrict__ row_start,
                                              float* __restrict__ r_in,
                                              int* __restrict__ csr) {
    __shared__ int cnt[128], cur[128];
    int tid = threadIdx.x;
    int b = blockIdx.x;
    int base = bucket_base[b], end = bucket_base[b + 1];
    if (tid < 128) cnt[tid] = 0;
    __syncthreads();
    for (int i = base + tid; i < end; i += 256) atomicAdd(&cnt[E2[i] & 127], 1);
    __syncthreads();
    int v = (tid < 128) ? cnt[tid] : 0;
    for (int off = 1; off < 128; off <<= 1) {
        int u = (tid >= off && tid < 128) ? cnt[tid - off] : 0;
        __syncthreads();
        if (tid < 128) cnt[tid] += u;
        __syncthreads();
    }
    if (tid < 128) {
        int excl = cnt[tid] - v;  // exclusive scan within bucket
        cur[tid] = excl;
        int node = b * 128 + tid;
        if (node <= NN) row_start[node] = base + excl;
        if (node < NN) r_in[node] = rsqrtf((float)max(v, 1));
    }
    __syncthreads();
    for (int i = base + tid; i < end; i += 256) {
        int e = E2[i];
        int pos = atomicAdd(&cur[e & 127], 1);
        csr[base + pos] = e >> 7;
    }
}

__global__ __launch_bounds__(256) void k_rout(const int* __restrict__ cnt_out,
                                              float* __restrict__ r_out) {
    int t = blockIdx.x * 256 + threadIdx.x;
    if (t < NN) r_out[t] = rsqrtf((float)max(cnt_out[t], 1));
}

// ---------------- dense GEMMs ----------------

// A(bf16) = (x @ W0) * r_out.  64 nodes/block, thread = 4m x 4n, K=128 in two halves.
__global__ __launch_bounds__(256) void k_gemm0(const float* __restrict__ x,
                                               const float* __restrict__ W0,
                                               const float* __restrict__ r_out,
                                               unsigned short* __restrict__ A) {
    __shared__ float xl[64 * 129];
    __shared__ float wl[64 * 64];
    int tid = threadIdx.x;
    int m0 = blockIdx.x * 64;
#pragma unroll
    for (int i = 0; i < 8; ++i) {
        int idx = i * 256 + tid;
        int m = idx >> 5, kc = idx & 31;
        int gm = min(m0 + m, NN - 1);
        float4 v = *(const float4*)&x[(size_t)gm * 128 + kc * 4];
        float* p = &xl[m * 129 + kc * 4];
        p[0] = v.x; p[1] = v.y; p[2] = v.z; p[3] = v.w;
    }
    int tn = tid & 15, tm = tid >> 4;
    float acc[4][4] = {};
    const float4* W4 = (const float4*)W0;
    float4* wl4 = (float4*)wl;
    for (int h = 0; h < 2; ++h) {
        __syncthreads();
#pragma unroll
        for (int i = 0; i < 4; ++i) wl4[i * 256 + tid] = W4[h * 1024 + i * 256 + tid];
        __syncthreads();
#pragma unroll 4
        for (int k = 0; k < 64; ++k) {
            int kk = h * 64 + k;
            float4 wv = *(const float4*)&wl[k * 64 + tn * 4];
            float xv[4];
#pragma unroll
            for (int i = 0; i < 4; ++i) xv[i] = xl[(tm * 4 + i) * 129 + kk];
#pragma unroll
            for (int i = 0; i < 4; ++i) {
                acc[i][0] = fmaf(xv[i], wv.x, acc[i][0]);
                acc[i][1] = fmaf(xv[i], wv.y, acc[i][1]);
                acc[i][2] = fmaf(xv[i], wv.z, acc[i][2]);
                acc[i][3] = fmaf(xv[i], wv.w, acc[i][3]);
            }
        }
    }
#pragma unroll
    for (int i = 0; i < 4; ++i) {
        int m = m0 + tm * 4 + i;
        if (m < NN) {
            float ro = r_out[m];
            US4 o = {f2bf(acc[i][0] * ro), f2bf(acc[i][1] * ro),
                     f2bf(acc[i][2] * ro), f2bf(acc[i][3] * ro)};
            *(US4*)&A[(size_t)m * 64 + tn * 4] = o;
        }
    }
}

// C = (relu(G @ W1 + b1) @ W2) * r_out.  G is bf16.  64 nodes/block.
__global__ __launch_bounds__(256) void k_mlp(const unsigned short* __restrict__ G,
                                             const float* __restrict__ W1,
                                             const float* __restrict__ b1,
                                             const float* __restrict__ W2,
                                             const float* __restrict__ r_out,
                                             float* __restrict__ C) {
    __shared__ float gl[64 * 65];
    __shared__ float w1l[64 * 64];
    __shared__ float w2l[64 * 16];
    int tid = threadIdx.x;
    int m0 = blockIdx.x * 64;
#pragma unroll
    for (int i = 0; i < 2; ++i) {
        int idx = i * 256 + tid;  // 512 chunks of 8 bf16
        int m = idx >> 3, c8 = idx & 7;
        int gm = min(m0 + m, NN - 1);
        uint4 u = *(const uint4*)&G[(size_t)gm * 64 + c8 * 8];
        float* p = &gl[m * 65 + c8 * 8];
        p[0] = bfu(u.x & 0xffffu); p[1] = bfu(u.x >> 16);
        p[2] = bfu(u.y & 0xffffu); p[3] = bfu(u.y >> 16);
        p[4] = bfu(u.z & 0xffffu); p[5] = bfu(u.z >> 16);
        p[6] = bfu(u.w & 0xffffu); p[7] = bfu(u.w >> 16);
    }
    float4* w1l4 = (float4*)w1l;
    const float4* W1_4 = (const float4*)W1;
#pragma unroll
    for (int i = 0; i < 4; ++i) w1l4[i * 256 + tid] = W1_4[i * 256 + tid];
    ((float4*)w2l)[tid] = ((const float4*)W2)[tid];
    __syncthreads();
    int tn = tid & 15, tm = tid >> 4;
    float acc[4][4] = {};
#pragma unroll 4
    for (int k = 0; k < 64; ++k) {
        float4 wv = *(const float4*)&w1l[k * 64 + tn * 4];
        float xv[4];
#pragma unroll
        for (int i = 0; i < 4; ++i) xv[i] = gl[(tm * 4 + i) * 65 + k];
#pragma unroll
        for (int i = 0; i < 4; ++i) {
            acc[i][0] = fmaf(xv[i], wv.x, acc[i][0]);
            acc[i][1] = fmaf(xv[i], wv.y, acc[i][1]);
            acc[i][2] = fmaf(xv[i], wv.z, acc[i][2]);
            acc[i][3] = fmaf(xv[i], wv.w, acc[i][3]);
        }
    }
    float4 bb = *(const float4*)&b1[tn * 4];
    __syncthreads();
#pragma unroll
    for (int i = 0; i < 4; ++i) {
        gl[(tm * 4 + i) * 65 + tn * 4 + 0] = fmaxf(acc[i][0] + bb.x, 0.f);
        gl[(tm * 4 + i) * 65 + tn * 4 + 1] = fmaxf(acc[i][1] + bb.y, 0.f);
        gl[(tm * 4 + i) * 65 + tn * 4 + 2] = fmaxf(acc[i][2] + bb.z, 0.f);
        gl[(tm * 4 + i) * 65 + tn * 4 + 3] = fmaxf(acc[i][3] + bb.w, 0.f);
    }
    __syncthreads();
    int m = tid >> 2, n0 = (tid & 3) * 4;
    float a2[4] = {};
#pragma unroll 8
    for (int k = 0; k < 64; ++k) {
        float zv = gl[m * 65 + k];
        float4 wv = *(const float4*)&w2l[k * 16 + n0];
        a2[0] = fmaf(zv, wv.x, a2[0]);
        a2[1] = fmaf(zv, wv.y, a2[1]);
        a2[2] = fmaf(zv, wv.z, a2[2]);
        a2[3] = fmaf(zv, wv.w, a2[3]);
    }
    int node = m0 + m;
    if (node < NN) {
        float ro = r_out[node];
        float4 o = {a2[0] * ro, a2[1] * ro, a2[2] * ro, a2[3] * ro};
        *(float4*)&C[(size_t)node * 16 + n0] = o;
    }
}

// ---------------- gathers (register-accumulate, per-node wave) ----------------

// d=64 bf16 gather, 1 node/wave, 16 edges in flight (4 groups x 4-deep ILP).
// MODE 0: o16 = bf16(relu(agg*r_in + bias)*r_out)   (layer0 -> B)
// MODE 1: o16 = bf16(agg*r_in)                      (layer1 -> G, feeds k_mlp)
template <int MODE>
__global__ __launch_bounds__(256) void k_gather64(const int* __restrict__ row_start,
                                                  const int* __restrict__ csr,
                                                  const unsigned short* __restrict__ h,
                                                  const float* __restrict__ r_in,
                                                  const float* __restrict__ r_out,
                                                  const float* __restrict__ bias,
                                                  unsigned short* __restrict__ o16) {
    int tid = threadIdx.x;
    int wave = tid >> 6, lane = tid & 63;
    int n = blockIdx.x * 4 + wave;
    int jb = row_start[n], je = row_start[n + 1];
    int g = lane >> 4, f = lane & 15;
    float4 a0 = {0, 0, 0, 0}, a1 = {0, 0, 0, 0};
    float4 a2 = {0, 0, 0, 0}, a3 = {0, 0, 0, 0};
    for (int j = jb; j < je; j += 16) {
        int i0 = j + g, i1 = i0 + 4, i2 = i0 + 8, i3 = i0 + 12;
        int s0 = csr[min(i0, je - 1)];
        int s1 = csr[min(i1, je - 1)];
        int s2 = csr[min(i2, je - 1)];
        int s3 = csr[min(i3, je - 1)];
        uint2 u0 = *(const uint2*)(h + (size_t)s0 * 64 + f * 4);
        uint2 u1 = *(const uint2*)(h + (size_t)s1 * 64 + f * 4);
        uint2 u2 = *(const uint2*)(h + (size_t)s2 * 64 + f * 4);
        uint2 u3 = *(const uint2*)(h + (size_t)s3 * 64 + f * 4);
        float w0 = (i0 < je) ? 1.f : 0.f;
        float w1 = (i1 < je) ? 1.f : 0.f;
        float w2 = (i2 < je) ? 1.f : 0.f;
        float w3 = (i3 < je) ? 1.f : 0.f;
        a0.x = fmaf(w0, bfu(u0.x & 0xffffu), a0.x);
        a0.y = fmaf(w0, bfu(u0.x >> 16), a0.y);
        a0.z = fmaf(w0, bfu(u0.y & 0xffffu), a0.z);
        a0.w = fmaf(w0, bfu(u0.y >> 16), a0.w);
        a1.x = fmaf(w1, bfu(u1.x & 0xffffu), a1.x);
        a1.y = fmaf(w1, bfu(u1.x >> 16), a1.y);
        a1.z = fmaf(w1, bfu(u1.y & 0xffffu), a1.z);
        a1.w = fmaf(w1, bfu(u1.y >> 16), a1.w);
        a2.x = fmaf(w2, bfu(u2.x & 0xffffu), a2.x);
        a2.y = fmaf(w2, bfu(u2.x >> 16), a2.y);
        a2.z = fmaf(w2, bfu(u2.y & 0xffffu), a2.z);
        a2.w = fmaf(w2, bfu(u2.y >> 16), a2.w);
        a3.x = fmaf(w3, bfu(u3.x & 0xffffu), a3.x);
        a3.y = fmaf(w3, bfu(u3.x >> 16), a3.y);
        a3.z = fmaf(w3, bfu(u3.y & 0xffffu), a3.z);
        a3.w = fmaf(w3, bfu(u3.y >> 16), a3.w);
    }
    a0.x += a1.x; a0.y += a1.y; a0.z += a1.z; a0.w += a1.w;
    a2.x += a3.x; a2.y += a3.y; a2.z += a3.z; a2.w += a3.w;
    a0.x += a2.x; a0.y += a2.y; a0.z += a2.z; a0.w += a2.w;
    a0.x += __shfl_xor(a0.x, 16); a0.y += __shfl_xor(a0.y, 16);
    a0.z += __shfl_xor(a0.z, 16); a0.w += __shfl_xor(a0.w, 16);
    a0.x += __shfl_xor(a0.x, 32); a0.y += __shfl_xor(a0.y, 32);
    a0.z += __shfl_xor(a0.z, 32); a0.w += __shfl_xor(a0.w, 32);
    if (g == 0) {
        float ri = r_in[n];
        US4 o;
        if (MODE == 0) {
            float ro = r_out[n];
            float4 bb = *(const float4*)&bias[f * 4];
            o.x = f2bf(fmaxf(fmaf(a0.x, ri, bb.x), 0.f) * ro);
            o.y = f2bf(fmaxf(fmaf(a0.y, ri, bb.y), 0.f) * ro);
            o.z = f2bf(fmaxf(fmaf(a0.z, ri, bb.z), 0.f) * ro);
            o.w = f2bf(fmaxf(fmaf(a0.w, ri, bb.w), 0.f) * ro);
        } else {
            o.x = f2bf(a0.x * ri); o.y = f2bf(a0.y * ri);
            o.z = f2bf(a0.z * ri); o.w = f2bf(a0.w * ri);
        }
        *(US4*)&o16[(size_t)n * 64 + f * 4] = o;
    }
}

// d=16 fp32 gather: out = agg*r_in + b2
__global__ __launch_bounds__(256) void k_gather16(const int* __restrict__ row_start,
                                                  const int* __restrict__ csr,
                                                  const float* __restrict__ C,
                                                  const float* __restrict__ r_in,
                                                  const float* __restrict__ b2,
                                                  float* __restrict__ out) {
    int tid = threadIdx.x;
    int wave = tid >> 6, lane = tid & 63;
    int n = blockIdx.x * 4 + wave;
    int jb = row_start[n], je = row_start[n + 1];
    int g = lane >> 2, f = lane & 3;
    float4 acc = {0, 0, 0, 0};
    for (int j = jb; j < je; j += 16) {
        int i0 = j + g;
        int s = csr[min(i0, je - 1)];
        float4 v = *(const float4*)&C[(size_t)s * 16 + f * 4];
        float w = (i0 < je) ? 1.f : 0.f;
        acc.x = fmaf(w, v.x, acc.x); acc.y = fmaf(w, v.y, acc.y);
        acc.z = fmaf(w, v.z, acc.z); acc.w = fmaf(w, v.w, acc.w);
    }
#pragma unroll
    for (int m = 4; m <= 32; m <<= 1) {
        acc.x += __shfl_xor(acc.x, m); acc.y += __shfl_xor(acc.y, m);
        acc.z += __shfl_xor(acc.z, m); acc.w += __shfl_xor(acc.w, m);
    }
    if (g == 0) {
        float ri = r_in[n];
        float4 bb = *(const float4*)&b2[f * 4];
        float4 o;
        o.x = fmaf(acc.x, ri, bb.x); o.y = fmaf(acc.y, ri, bb.y);
        o.z = fmaf(acc.z, ri, bb.z); o.w = fmaf(acc.w, ri, bb.w);
        *(float4*)&out[(size_t)n * 16 + f * 4] = o;
    }
}

extern "C" void kernel_launch(void* const* d_in, const int* in_sizes, int n_in,
                              void* d_out, int out_size, void* d_ws, size_t ws_size,
                              hipStream_t stream) {
    const float* feats = (const float*)d_in[0];
    const int* src = (const int*)d_in[1];
    const int* dst = (const int*)d_in[2];
    const float* W0 = (const float*)d_in[3];
    const float* b0 = (const float*)d_in[4];
    const float* W1 = (const float*)d_in[5];
    const float* b1 = (const float*)d_in[6];
    const float* W2 = (const float*)d_in[7];
    const float* b2 = (const float*)d_in[8];
    float* out = (float*)d_out;

    // ws (float units):
    //   r_out[NN] | r_in[NN] | row_start[NN+16] | csr[NE] |
    //   R1[32NN]  (E2[NE ints] then A[bf16 64NN] then G[bf16 64NN])
    //   R2[32NN]  (cnt_out[NN]+bucket_cnt[NBUCK] ints transient, then B[bf16 64NN])
    //   C[16NN] f32 | bucket_base[NBUCK+1] | bucket_cursor[NBUCK]
    float* ws = (float*)d_ws;
    float* r_out = ws;
    float* r_in = ws + NN;
    int* row_start = (int*)(ws + 2 * NN);
    int* csr = (int*)(ws + 3 * NN + 16);
    float* R1 = ws + 3 * NN + 16 + NE;
    float* R2 = R1 + (size_t)32 * NN;
    float* C = R2 + (size_t)32 * NN;
    int* bucket_base = (int*)(C + (size_t)16 * NN);  // NBUCK+1
    int* bucket_cursor = bucket_base + NBUCK + 1;    // NBUCK

    int* E2 = (int*)R1;
    unsigned short* A = (unsigned short*)R1;  // after bcsr (E2 dead)
    unsigned short* G = A;                    // after gather<0> (A dead)
    int* cnt_out = (int*)R2;                  // transient, dead after k_rout
    int* bucket_cnt = cnt_out + NN;
    unsigned short* B = (unsigned short*)R2;  // after k_rout

    // build
    hipMemsetAsync(cnt_out, 0, (NN + NBUCK) * sizeof(int), stream);
    k_hist<<<HISTB, 256, 0, stream>>>(src, dst, cnt_out, bucket_cnt);
    k_bscan<<<1, 1024, 0, stream>>>(bucket_cnt, bucket_base, bucket_cursor);
    k_pairs<<<(NE + PCHUNK - 1) / PCHUNK, 256, 0, stream>>>(src, dst, bucket_cursor, E2);
    k_bcsr<<<NBUCK, 256, 0, stream>>>(E2, bucket_base, row_start, r_in, csr);
    k_rout<<<(NN + 255) / 256, 256, 0, stream>>>(cnt_out, r_out);

    // layer 0
    k_gemm0<<<(NN + 63) / 64, 256, 0, stream>>>(feats, W0, r_out, A);
    k_gather64<0><<<NN / 4, 256, 0, stream>>>(row_start, csr, A, r_in, r_out, b0, B);

    // layer 1 (+ layer2 pre-GEMM)
    k_gather64<1><<<NN / 4, 256, 0, stream>>>(row_start, csr, B, r_in, r_out, b0, G);
    k_mlp<<<(NN + 63) / 64, 256, 0, stream>>>(G, W1, b1, W2, r_out, C);

    // layer 2
    k_gather16<<<NN / 4, 256, 0, stream>>>(row_start, csr, C, r_in, b2, out);
}

// Round 8
// 397.800 us; speedup vs baseline: 1.0256x; 1.0256x over previous
//
#include <hip/hip_runtime.h>

#define NN 100000
#define NE 1600000
#define NBUCK 782   // ceil(NN/128), bucket = dst >> 7
#define PCHUNK 8192 // edges per k_pairs block
#define HISTB 784   // k_hist grid
#define NREP 8      // replicated counter copies (one per XCD slice)

struct alignas(8) US4 { unsigned short x, y, z, w; };

__device__ __forceinline__ float bfu(unsigned int hw) { return __uint_as_float(hw << 16); }
__device__ __forceinline__ unsigned short f2bf(float f) {
    unsigned int u = __float_as_uint(f);
    return (unsigned short)((u + 0x7fffu + ((u >> 16) & 1u)) >> 16);
}

// ---------------- build: bucket-ordered packed edges -> per-node CSR ----------------

// replicated histogram: copy (blockIdx&7) keeps atomic lines XCD-local
__global__ __launch_bounds__(256) void k_hist(const int* __restrict__ src,
                                              const int* __restrict__ dst,
                                              int* __restrict__ cnt_out8,
                                              int* __restrict__ bucket_cnt8) {
    __shared__ int hist[NBUCK];
    int tid = threadIdx.x;
    int* my_cnt = cnt_out8 + (size_t)(blockIdx.x & (NREP - 1)) * NN;
    int* my_bcnt = bucket_cnt8 + (size_t)(blockIdx.x & (NREP - 1)) * NBUCK;
    for (int i = tid; i < NBUCK; i += 256) hist[i] = 0;
    __syncthreads();
    int stride = gridDim.x * 256;
    for (int e = blockIdx.x * 256 + tid; e < NE; e += stride) {
        atomicAdd(&hist[dst[e] >> 7], 1);
        atomicAdd(&my_cnt[src[e]], 1);
    }
    __syncthreads();
    for (int i = tid; i < NBUCK; i += 256)
        if (hist[i]) atomicAdd(&my_bcnt[i], hist[i]);
}

__global__ __launch_bounds__(1024) void k_bscan(const int* __restrict__ bucket_cnt8,
                                                int* __restrict__ bucket_base,
                                                int* __restrict__ bucket_cursor) {
    __shared__ int tmp[1024];
    int t = threadIdx.x;
    int v = 0;
    if (t < NBUCK)
#pragma unroll
        for (int c = 0; c < NREP; ++c) v += bucket_cnt8[c * NBUCK + t];
    tmp[t] = v;
    __syncthreads();
    for (int off = 1; off < 1024; off <<= 1) {
        int u = (t >= off) ? tmp[t - off] : 0;
        __syncthreads();
        tmp[t] += u;
        __syncthreads();
    }
    int excl = tmp[t] - v;
    if (t < NBUCK) {
        bucket_base[t] = excl;
        bucket_cursor[t] = excl;
    }
    if (t == 0) bucket_base[NBUCK] = NE;
}

// LDS-binned scatter: bulk range reservation per (block,bucket), then packed
// (src<<7 | dst&127) words written into per-block contiguous runs.
__global__ __launch_bounds__(256) void k_pairs(const int* __restrict__ src,
                                               const int* __restrict__ dst,
                                               int* __restrict__ bucket_cursor,
                                               int* __restrict__ E2) {
    __shared__ int hist[NBUCK], gbase[NBUCK];
    int tid = threadIdx.x;
    for (int i = tid; i < NBUCK; i += 256) hist[i] = 0;
    __syncthreads();
    int base = blockIdx.x * PCHUNK;
#pragma unroll
    for (int i = 0; i < PCHUNK / 256; ++i) {
        int e = base + i * 256 + tid;
        if (e < NE) atomicAdd(&hist[dst[e] >> 7], 1);
    }
    __syncthreads();
    for (int i = tid; i < NBUCK; i += 256) {
        int h = hist[i];
        if (h) gbase[i] = atomicAdd(&bucket_cursor[i], h);
        hist[i] = 0;
    }
    __syncthreads();
#pragma unroll
    for (int i = 0; i < PCHUNK / 256; ++i) {
        int e = base + i * 256 + tid;
        if (e < NE) {
            int d = dst[e];
            int b = d >> 7;
            int pos = atomicAdd(&hist[b], 1);
            E2[gbase[b] + pos] = (src[e] << 7) | (d & 127);
        }
    }
}

// per-bucket: LDS count+scan+cursor -> row_start, r_in, csr (block-local writes)
__global__ __launch_bounds__(256) void k_bcsr(const int* __restrict__ E2,
                                              const int* __restrict__ bucket_base,
                                              int* __restrict__ row_start,
                                              float* __restrict__ r_in,
                                              int* __restrict__ csr) {
    __shared__ int cnt[128], cur[128];
    int tid = threadIdx.x;
    int b = blockIdx.x;
    int base = bucket_base[b], end = bucket_base[b + 1];
    if (tid < 128) cnt[tid] = 0;
    __syncthreads();
    for (int i = base + tid; i < end; i += 256) atomicAdd(&cnt[E2[i] & 127], 1);
    __syncthreads();
    int v = (tid < 128) ? cnt[tid] : 0;
    for (int off = 1; off < 128; off <<= 1) {
        int u = (tid >= off && tid < 128) ? cnt[tid - off] : 0;
        __syncthreads();
        if (tid < 128) cnt[tid] += u;
        __syncthreads();
    }
    if (tid < 128) {
        int excl = cnt[tid] - v;  // exclusive scan within bucket
        cur[tid] = excl;
        int node = b * 128 + tid;
        if (node <= NN) row_start[node] = base + excl;
        if (node < NN) r_in[node] = rsqrtf((float)max(v, 1));
    }
    __syncthreads();
    for (int i = base + tid; i < end; i += 256) {
        int e = E2[i];
        int pos = atomicAdd(&cur[e & 127], 1);
        csr[base + pos] = e >> 7;
    }
}

__global__ __launch_bounds__(256) void k_rout(const int* __restrict__ cnt_out8,
                                              float* __restrict__ r_out) {
    int t = blockIdx.x * 256 + threadIdx.x;
    if (t < NN) {
        int s = 0;
#pragma unroll
        for (int c = 0; c < NREP; ++c) s += cnt_out8[(size_t)c * NN + t];
        r_out[t] = rsqrtf((float)max(s, 1));
    }
}

// ---------------- dense GEMMs ----------------

// A(bf16) = (x @ W0) * r_out.  64 nodes/block, thread = 4m x 4n, K=128 in two halves.
__global__ __launch_bounds__(256) void k_gemm0(const float* __restrict__ x,
                                               const float* __restrict__ W0,
                                               const float* __restrict__ r_out,
                                               unsigned short* __restrict__ A) {
    __shared__ float xl[64 * 129];
    __shared__ float wl[64 * 64];
    int tid = threadIdx.x;
    int m0 = blockIdx.x * 64;
#pragma unroll
    for (int i = 0; i < 8; ++i) {
        int idx = i * 256 + tid;
        int m = idx >> 5, kc = idx & 31;
        int gm = min(m0 + m, NN - 1);
        float4 v = *(const float4*)&x[(size_t)gm * 128 + kc * 4];
        float* p = &xl[m * 129 + kc * 4];
        p[0] = v.x; p[1] = v.y; p[2] = v.z; p[3] = v.w;
    }
    int tn = tid & 15, tm = tid >> 4;
    float acc[4][4] = {};
    const float4* W4 = (const float4*)W0;
    float4* wl4 = (float4*)wl;
    for (int h = 0; h < 2; ++h) {
        __syncthreads();
#pragma unroll
        for (int i = 0; i < 4; ++i) wl4[i * 256 + tid] = W4[h * 1024 + i * 256 + tid];
        __syncthreads();
#pragma unroll 4
        for (int k = 0; k < 64; ++k) {
            int kk = h * 64 + k;
            float4 wv = *(const float4*)&wl[k * 64 + tn * 4];
            float xv[4];
#pragma unroll
            for (int i = 0; i < 4; ++i) xv[i] = xl[(tm * 4 + i) * 129 + kk];
#pragma unroll
            for (int i = 0; i < 4; ++i) {
                acc[i][0] = fmaf(xv[i], wv.x, acc[i][0]);
                acc[i][1] = fmaf(xv[i], wv.y, acc[i][1]);
                acc[i][2] = fmaf(xv[i], wv.z, acc[i][2]);
                acc[i][3] = fmaf(xv[i], wv.w, acc[i][3]);
            }
        }
    }
#pragma unroll
    for (int i = 0; i < 4; ++i) {
        int m = m0 + tm * 4 + i;
        if (m < NN) {
            float ro = r_out[m];
            US4 o = {f2bf(acc[i][0] * ro), f2bf(acc[i][1] * ro),
                     f2bf(acc[i][2] * ro), f2bf(acc[i][3] * ro)};
            *(US4*)&A[(size_t)m * 64 + tn * 4] = o;
        }
    }
}

// C = (relu(G @ W1 + b1) @ W2) * r_out.  G is bf16.  64 nodes/block.
__global__ __launch_bounds__(256) void k_mlp(const unsigned short* __restrict__ G,
                                             const float* __restrict__ W1,
                                             const float* __restrict__ b1,
                                             const float* __restrict__ W2,
                                             const float* __restrict__ r_out,
                                             float* __restrict__ C) {
    __shared__ float gl[64 * 65];
    __shared__ float w1l[64 * 64];
    __shared__ float w2l[64 * 16];
    int tid = threadIdx.x;
    int m0 = blockIdx.x * 64;
#pragma unroll
    for (int i = 0; i < 2; ++i) {
        int idx = i * 256 + tid;  // 512 chunks of 8 bf16
        int m = idx >> 3, c8 = idx & 7;
        int gm = min(m0 + m, NN - 1);
        uint4 u = *(const uint4*)&G[(size_t)gm * 64 + c8 * 8];
        float* p = &gl[m * 65 + c8 * 8];
        p[0] = bfu(u.x & 0xffffu); p[1] = bfu(u.x >> 16);
        p[2] = bfu(u.y & 0xffffu); p[3] = bfu(u.y >> 16);
        p[4] = bfu(u.z & 0xffffu); p[5] = bfu(u.z >> 16);
        p[6] = bfu(u.w & 0xffffu); p[7] = bfu(u.w >> 16);
    }
    float4* w1l4 = (float4*)w1l;
    const float4* W1_4 = (const float4*)W1;
#pragma unroll
    for (int i = 0; i < 4; ++i) w1l4[i * 256 + tid] = W1_4[i * 256 + tid];
    ((float4*)w2l)[tid] = ((const float4*)W2)[tid];
    __syncthreads();
    int tn = tid & 15, tm = tid >> 4;
    float acc[4][4] = {};
#pragma unroll 4
    for (int k = 0; k < 64; ++k) {
        float4 wv = *(const float4*)&w1l[k * 64 + tn * 4];
        float xv[4];
#pragma unroll
        for (int i = 0; i < 4; ++i) xv[i] = gl[(tm * 4 + i) * 65 + k];
#pragma unroll
        for (int i = 0; i < 4; ++i) {
            acc[i][0] = fmaf(xv[i], wv.x, acc[i][0]);
            acc[i][1] = fmaf(xv[i], wv.y, acc[i][1]);
            acc[i][2] = fmaf(xv[i], wv.z, acc[i][2]);
            acc[i][3] = fmaf(xv[i], wv.w, acc[i][3]);
        }
    }
    float4 bb = *(const float4*)&b1[tn * 4];
    __syncthreads();
#pragma unroll
    for (int i = 0; i < 4; ++i) {
        gl[(tm * 4 + i) * 65 + tn * 4 + 0] = fmaxf(acc[i][0] + bb.x, 0.f);
        gl[(tm * 4 + i) * 65 + tn * 4 + 1] = fmaxf(acc[i][1] + bb.y, 0.f);
        gl[(tm * 4 + i) * 65 + tn * 4 + 2] = fmaxf(acc[i][2] + bb.z, 0.f);
        gl[(tm * 4 + i) * 65 + tn * 4 + 3] = fmaxf(acc[i][3] + bb.w, 0.f);
    }
    __syncthreads();
    int m = tid >> 2, n0 = (tid & 3) * 4;
    float a2[4] = {};
#pragma unroll 8
    for (int k = 0; k < 64; ++k) {
        float zv = gl[m * 65 + k];
        float4 wv = *(const float4*)&w2l[k * 16 + n0];
        a2[0] = fmaf(zv, wv.x, a2[0]);
        a2[1] = fmaf(zv, wv.y, a2[1]);
        a2[2] = fmaf(zv, wv.z, a2[2]);
        a2[3] = fmaf(zv, wv.w, a2[3]);
    }
    int node = m0 + m;
    if (node < NN) {
        float ro = r_out[node];
        float4 o = {a2[0] * ro, a2[1] * ro, a2[2] * ro, a2[3] * ro};
        *(float4*)&C[(size_t)node * 16 + n0] = o;
    }
}

// ---------------- gathers (register-accumulate, per-node wave) ----------------

// d=64 bf16 gather, 1 node/wave, 16 edges in flight (4 groups x 4-deep ILP).
// MODE 0: o16 = bf16(relu(agg*r_in + bias)*r_out)   (layer0 -> B)
// MODE 1: o16 = bf16(agg*r_in)                      (layer1 -> G, feeds k_mlp)
template <int MODE>
__global__ __launch_bounds__(256) void k_gather64(const int* __restrict__ row_start,
                                                  const int* __restrict__ csr,
                                                  const unsigned short* __restrict__ h,
                                                  const float* __restrict__ r_in,
                                                  const float* __restrict__ r_out,
                                                  const float* __restrict__ bias,
                                                  unsigned short* __restrict__ o16) {
    int tid = threadIdx.x;
    int wave = tid >> 6, lane = tid & 63;
    int n = blockIdx.x * 4 + wave;
    int jb = row_start[n], je = row_start[n + 1];
    int g = lane >> 4, f = lane & 15;
    float4 a0 = {0, 0, 0, 0}, a1 = {0, 0, 0, 0};
    float4 a2 = {0, 0, 0, 0}, a3 = {0, 0, 0, 0};
    for (int j = jb; j < je; j += 16) {
        int i0 = j + g, i1 = i0 + 4, i2 = i0 + 8, i3 = i0 + 12;
        int s0 = csr[min(i0, je - 1)];
        int s1 = csr[min(i1, je - 1)];
        int s2 = csr[min(i2, je - 1)];
        int s3 = csr[min(i3, je - 1)];
        uint2 u0 = *(const uint2*)(h + (size_t)s0 * 64 + f * 4);
        uint2 u1 = *(const uint2*)(h + (size_t)s1 * 64 + f * 4);
        uint2 u2 = *(const uint2*)(h + (size_t)s2 * 64 + f * 4);
        uint2 u3 = *(const uint2*)(h + (size_t)s3 * 64 + f * 4);
        float w0 = (i0 < je) ? 1.f : 0.f;
        float w1 = (i1 < je) ? 1.f : 0.f;
        float w2 = (i2 < je) ? 1.f : 0.f;
        float w3 = (i3 < je) ? 1.f : 0.f;
        a0.x = fmaf(w0, bfu(u0.x & 0xffffu), a0.x);
        a0.y = fmaf(w0, bfu(u0.x >> 16), a0.y);
        a0.z = fmaf(w0, bfu(u0.y & 0xffffu), a0.z);
        a0.w = fmaf(w0, bfu(u0.y >> 16), a0.w);
        a1.x = fmaf(w1, bfu(u1.x & 0xffffu), a1.x);
        a1.y = fmaf(w1, bfu(u1.x >> 16), a1.y);
        a1.z = fmaf(w1, bfu(u1.y & 0xffffu), a1.z);
        a1.w = fmaf(w1, bfu(u1.y >> 16), a1.w);
        a2.x = fmaf(w2, bfu(u2.x & 0xffffu), a2.x);
        a2.y = fmaf(w2, bfu(u2.x >> 16), a2.y);
        a2.z = fmaf(w2, bfu(u2.y & 0xffffu), a2.z);
        a2.w = fmaf(w2, bfu(u2.y >> 16), a2.w);
        a3.x = fmaf(w3, bfu(u3.x & 0xffffu), a3.x);
        a3.y = fmaf(w3, bfu(u3.x >> 16), a3.y);
        a3.z = fmaf(w3, bfu(u3.y & 0xffffu), a3.z);
        a3.w = fmaf(w3, bfu(u3.y >> 16), a3.w);
    }
    a0.x += a1.x; a0.y += a1.y; a0.z += a1.z; a0.w += a1.w;
    a2.x += a3.x; a2.y += a3.y; a2.z += a3.z; a2.w += a3.w;
    a0.x += a2.x; a0.y += a2.y; a0.z += a2.z; a0.w += a2.w;
    a0.x += __shfl_xor(a0.x, 16); a0.y += __shfl_xor(a0.y, 16);
    a0.z += __shfl_xor(a0.z, 16); a0.w += __shfl_xor(a0.w, 16);
    a0.x += __shfl_xor(a0.x, 32); a0.y += __shfl_xor(a0.y, 32);
    a0.z += __shfl_xor(a0.z, 32); a0.w += __shfl_xor(a0.w, 32);
    if (g == 0) {
        float ri = r_in[n];
        US4 o;
        if (MODE == 0) {
            float ro = r_out[n];
            float4 bb = *(const float4*)&bias[f * 4];
            o.x = f2bf(fmaxf(fmaf(a0.x, ri, bb.x), 0.f) * ro);
            o.y = f2bf(fmaxf(fmaf(a0.y, ri, bb.y), 0.f) * ro);
            o.z = f2bf(fmaxf(fmaf(a0.z, ri, bb.z), 0.f) * ro);
            o.w = f2bf(fmaxf(fmaf(a0.w, ri, bb.w), 0.f) * ro);
        } else {
            o.x = f2bf(a0.x * ri); o.y = f2bf(a0.y * ri);
            o.z = f2bf(a0.z * ri); o.w = f2bf(a0.w * ri);
        }
        *(US4*)&o16[(size_t)n * 64 + f * 4] = o;
    }
}

// d=16 fp32 gather: out = agg*r_in + b2
__global__ __launch_bounds__(256) void k_gather16(const int* __restrict__ row_start,
                                                  const int* __restrict__ csr,
                                                  const float* __restrict__ C,
                                                  const float* __restrict__ r_in,
                                                  const float* __restrict__ b2,
                                                  float* __restrict__ out) {
    int tid = threadIdx.x;
    int wave = tid >> 6, lane = tid & 63;
    int n = blockIdx.x * 4 + wave;
    int jb = row_start[n], je = row_start[n + 1];
    int g = lane >> 2, f = lane & 3;
    float4 acc = {0, 0, 0, 0};
    for (int j = jb; j < je; j += 16) {
        int i0 = j + g;
        int s = csr[min(i0, je - 1)];
        float4 v = *(const float4*)&C[(size_t)s * 16 + f * 4];
        float w = (i0 < je) ? 1.f : 0.f;
        acc.x = fmaf(w, v.x, acc.x); acc.y = fmaf(w, v.y, acc.y);
        acc.z = fmaf(w, v.z, acc.z); acc.w = fmaf(w, v.w, acc.w);
    }
#pragma unroll
    for (int m = 4; m <= 32; m <<= 1) {
        acc.x += __shfl_xor(acc.x, m); acc.y += __shfl_xor(acc.y, m);
        acc.z += __shfl_xor(acc.z, m); acc.w += __shfl_xor(acc.w, m);
    }
    if (g == 0) {
        float ri = r_in[n];
        float4 bb = *(const float4*)&b2[f * 4];
        float4 o;
        o.x = fmaf(acc.x, ri, bb.x); o.y = fmaf(acc.y, ri, bb.y);
        o.z = fmaf(acc.z, ri, bb.z); o.w = fmaf(acc.w, ri, bb.w);
        *(float4*)&out[(size_t)n * 16 + f * 4] = o;
    }
}

extern "C" void kernel_launch(void* const* d_in, const int* in_sizes, int n_in,
                              void* d_out, int out_size, void* d_ws, size_t ws_size,
                              hipStream_t stream) {
    const float* feats = (const float*)d_in[0];
    const int* src = (const int*)d_in[1];
    const int* dst = (const int*)d_in[2];
    const float* W0 = (const float*)d_in[3];
    const float* b0 = (const float*)d_in[4];
    const float* W1 = (const float*)d_in[5];
    const float* b1 = (const float*)d_in[6];
    const float* W2 = (const float*)d_in[7];
    const float* b2 = (const float*)d_in[8];
    float* out = (float*)d_out;

    // ws (float units):
    //   r_out[NN] | r_in[NN] | row_start[NN+16] | csr[NE] |
    //   R1[32NN]  (E2[NE ints] then A[bf16 64NN] then G[bf16 64NN])
    //   R2[32NN]  (cnt_out8[8NN]+bucket_cnt8[8*NBUCK] ints transient, then B[bf16 64NN])
    //   C[16NN] f32 | bucket_base[NBUCK+1] | bucket_cursor[NBUCK]
    float* ws = (float*)d_ws;
    float* r_out = ws;
    float* r_in = ws + NN;
    int* row_start = (int*)(ws + 2 * NN);
    int* csr = (int*)(ws + 3 * NN + 16);
    float* R1 = ws + 3 * NN + 16 + NE;
    float* R2 = R1 + (size_t)32 * NN;
    float* C = R2 + (size_t)32 * NN;
    int* bucket_base = (int*)(C + (size_t)16 * NN);  // NBUCK+1
    int* bucket_cursor = bucket_base + NBUCK + 1;    // NBUCK

    int* E2 = (int*)R1;
    unsigned short* A = (unsigned short*)R1;  // after bcsr (E2 dead)
    unsigned short* G = A;                    // after gather<0> (A dead)
    int* cnt_out8 = (int*)R2;                 // transient 8*NN, dead after k_rout
    int* bucket_cnt8 = cnt_out8 + (size_t)NREP * NN;  // transient 8*NBUCK
    unsigned short* B = (unsigned short*)R2;  // after k_rout

    // build
    hipMemsetAsync(cnt_out8, 0, (size_t)NREP * (NN + NBUCK) * sizeof(int), stream);
    k_hist<<<HISTB, 256, 0, stream>>>(src, dst, cnt_out8, bucket_cnt8);
    k_bscan<<<1, 1024, 0, stream>>>(bucket_cnt8, bucket_base, bucket_cursor);
    k_pairs<<<(NE + PCHUNK - 1) / PCHUNK, 256, 0, stream>>>(src, dst, bucket_cursor, E2);
    k_bcsr<<<NBUCK, 256, 0, stream>>>(E2, bucket_base, row_start, r_in, csr);
    k_rout<<<(NN + 255) / 256, 256, 0, stream>>>(cnt_out8, r_out);

    // layer 0
    k_gemm0<<<(NN + 63) / 64, 256, 0, stream>>>(feats, W0, r_out, A);
    k_gather64<0><<<NN / 4, 256, 0, stream>>>(row_start, csr, A, r_in, r_out, b0, B);

    // layer 1 (+ layer2 pre-GEMM)
    k_gather64<1><<<NN / 4, 256, 0, stream>>>(row_start, csr, B, r_in, r_out, b0, G);
    k_mlp<<<(NN + 63) / 64, 256, 0, stream>>>(G, W1, b1, W2, r_out, C);

    // layer 2
    k_gather16<<<NN / 4, 256, 0, stream>>>(row_start, csr, C, r_in, b2, out);
}

// Round 9
// 359.503 us; speedup vs baseline: 1.1349x; 1.1065x over previous
//
#include <hip/hip_runtime.h>

#define NN 100000
#define NE 1600000
#define NBUCK 782   // ceil(NN/128), bucket = node >> 7
#define PCHUNK 8192 // edges per k_pairs block
#define HISTB 256   // k_hist grid
#define NREP 8      // replicated bucket-count copies

struct alignas(8) US4 { unsigned short x, y, z, w; };

__device__ __forceinline__ float bfu(unsigned int hw) { return __uint_as_float(hw << 16); }
__device__ __forceinline__ unsigned short f2bf(float f) {
    unsigned int u = __float_as_uint(f);
    return (unsigned short)((u + 0x7fffu + ((u >> 16) & 1u)) >> 16);
}

// ---------------- build: dual bucket-ordered edge arrays ----------------

// LDS-only dual histogram (dst buckets + src buckets), replicated global merge.
__global__ __launch_bounds__(256) void k_hist(const int* __restrict__ src,
                                              const int* __restrict__ dst,
                                              int* __restrict__ bcnt8_d,
                                              int* __restrict__ bcnt8_s) {
    __shared__ int hd[NBUCK], hs[NBUCK];
    int tid = threadIdx.x;
    for (int i = tid; i < NBUCK; i += 256) { hd[i] = 0; hs[i] = 0; }
    __syncthreads();
    int* md = bcnt8_d + (size_t)(blockIdx.x & (NREP - 1)) * NBUCK;
    int* ms = bcnt8_s + (size_t)(blockIdx.x & (NREP - 1)) * NBUCK;
    int stride = gridDim.x * 256;
    for (int e = blockIdx.x * 256 + tid; e < NE; e += stride) {
        atomicAdd(&hd[dst[e] >> 7], 1);
        atomicAdd(&hs[src[e] >> 7], 1);
    }
    __syncthreads();
    for (int i = tid; i < NBUCK; i += 256) {
        if (hd[i]) atomicAdd(&md[i], hd[i]);
        if (hs[i]) atomicAdd(&ms[i], hs[i]);
    }
}

// block 0: scan dst buckets; block 1: scan src buckets
__global__ __launch_bounds__(1024) void k_bscan(const int* __restrict__ bcnt8_d,
                                                const int* __restrict__ bcnt8_s,
                                                int* __restrict__ base_d,
                                                int* __restrict__ cursor_d,
                                                int* __restrict__ base_s,
                                                int* __restrict__ cursor_s) {
    __shared__ int tmp[1024];
    int t = threadIdx.x;
    const int* bc = blockIdx.x ? bcnt8_s : bcnt8_d;
    int* base = blockIdx.x ? base_s : base_d;
    int* cur = blockIdx.x ? cursor_s : cursor_d;
    int v = 0;
    if (t < NBUCK)
#pragma unroll
        for (int c = 0; c < NREP; ++c) v += bc[c * NBUCK + t];
    tmp[t] = v;
    __syncthreads();
    for (int off = 1; off < 1024; off <<= 1) {
        int u = (t >= off) ? tmp[t - off] : 0;
        __syncthreads();
        tmp[t] += u;
        __syncthreads();
    }
    int excl = tmp[t] - v;
    if (t < NBUCK) {
        base[t] = excl;
        cur[t] = excl;
    }
    if (t == 0) base[NBUCK] = NE;
}

// dual LDS-binned scatter: bulk reservation per (block,bucket), packed words
// into per-block contiguous runs.  E2d = (src<<7)|(dst&127); E2s = src&127.
__global__ __launch_bounds__(256) void k_pairs(const int* __restrict__ src,
                                               const int* __restrict__ dst,
                                               int* __restrict__ cursor_d,
                                               int* __restrict__ cursor_s,
                                               int* __restrict__ E2d,
                                               int* __restrict__ E2s) {
    __shared__ int hist_d[NBUCK], gbase_d[NBUCK], hist_s[NBUCK], gbase_s[NBUCK];
    int tid = threadIdx.x;
    for (int i = tid; i < NBUCK; i += 256) { hist_d[i] = 0; hist_s[i] = 0; }
    __syncthreads();
    int base = blockIdx.x * PCHUNK;
#pragma unroll
    for (int i = 0; i < PCHUNK / 256; ++i) {
        int e = base + i * 256 + tid;
        if (e < NE) {
            atomicAdd(&hist_d[dst[e] >> 7], 1);
            atomicAdd(&hist_s[src[e] >> 7], 1);
        }
    }
    __syncthreads();
    for (int i = tid; i < NBUCK; i += 256) {
        int h = hist_d[i];
        if (h) gbase_d[i] = atomicAdd(&cursor_d[i], h);
        hist_d[i] = 0;
        h = hist_s[i];
        if (h) gbase_s[i] = atomicAdd(&cursor_s[i], h);
        hist_s[i] = 0;
    }
    __syncthreads();
#pragma unroll
    for (int i = 0; i < PCHUNK / 256; ++i) {
        int e = base + i * 256 + tid;
        if (e < NE) {
            int s = src[e], d = dst[e];
            int bd = d >> 7;
            int pd = atomicAdd(&hist_d[bd], 1);
            E2d[gbase_d[bd] + pd] = (s << 7) | (d & 127);
            int bs = s >> 7;
            int ps = atomicAdd(&hist_s[bs], 1);
            E2s[gbase_s[bs] + ps] = s & 127;
        }
    }
}

// per src-bucket: LDS count -> r_out (out-degree rsqrt), no scatter atomics
__global__ __launch_bounds__(256) void k_socnt(const int* __restrict__ E2s,
                                               const int* __restrict__ base_s,
                                               float* __restrict__ r_out) {
    __shared__ int cnt[128];
    int tid = threadIdx.x;
    int b = blockIdx.x;
    int base = base_s[b], end = base_s[b + 1];
    if (tid < 128) cnt[tid] = 0;
    __syncthreads();
    for (int i = base + tid; i < end; i += 256) atomicAdd(&cnt[E2s[i]], 1);
    __syncthreads();
    if (tid < 128) {
        int node = b * 128 + tid;
        if (node < NN) r_out[node] = rsqrtf((float)max(cnt[tid], 1));
    }
}

// per dst-bucket: LDS count+scan+cursor -> row_start, r_in, csr (block-local writes)
__global__ __launch_bounds__(256) void k_bcsr(const int* __restrict__ E2d,
                                              const int* __restrict__ base_d,
                                              int* __restrict__ row_start,
                                              float* __restrict__ r_in,
                                              int* __restrict__ csr) {
    __shared__ int cnt[128], cur[128];
    int tid = threadIdx.x;
    int b = blockIdx.x;
    int base = base_d[b], end = base_d[b + 1];
    if (tid < 128) cnt[tid] = 0;
    __syncthreads();
    for (int i = base + tid; i < end; i += 256) atomicAdd(&cnt[E2d[i] & 127], 1);
    __syncthreads();
    int v = (tid < 128) ? cnt[tid] : 0;
    for (int off = 1; off < 128; off <<= 1) {
        int u = (tid >= off && tid < 128) ? cnt[tid - off] : 0;
        __syncthreads();
        if (tid < 128) cnt[tid] += u;
        __syncthreads();
    }
    if (tid < 128) {
        int excl = cnt[tid] - v;  // exclusive scan within bucket
        cur[tid] = excl;
        int node = b * 128 + tid;
        if (node <= NN) row_start[node] = base + excl;
        if (node < NN) r_in[node] = rsqrtf((float)max(v, 1));
    }
    __syncthreads();
    for (int i = base + tid; i < end; i += 256) {
        int e = E2d[i];
        int pos = atomicAdd(&cur[e & 127], 1);
        csr[base + pos] = e >> 7;
    }
}

// ---------------- dense GEMMs ----------------

// A(bf16) = (x @ W0) * r_out.  64 nodes/block, thread = 4m x 4n, K=128 in two halves.
__global__ __launch_bounds__(256) void k_gemm0(const float* __restrict__ x,
                                               const float* __restrict__ W0,
                                               const float* __restrict__ r_out,
                                               unsigned short* __restrict__ A) {
    __shared__ float xl[64 * 129];
    __shared__ float wl[64 * 64];
    int tid = threadIdx.x;
    int m0 = blockIdx.x * 64;
#pragma unroll
    for (int i = 0; i < 8; ++i) {
        int idx = i * 256 + tid;
        int m = idx >> 5, kc = idx & 31;
        int gm = min(m0 + m, NN - 1);
        float4 v = *(const float4*)&x[(size_t)gm * 128 + kc * 4];
        float* p = &xl[m * 129 + kc * 4];
        p[0] = v.x; p[1] = v.y; p[2] = v.z; p[3] = v.w;
    }
    int tn = tid & 15, tm = tid >> 4;
    float acc[4][4] = {};
    const float4* W4 = (const float4*)W0;
    float4* wl4 = (float4*)wl;
    for (int h = 0; h < 2; ++h) {
        __syncthreads();
#pragma unroll
        for (int i = 0; i < 4; ++i) wl4[i * 256 + tid] = W4[h * 1024 + i * 256 + tid];
        __syncthreads();
#pragma unroll 4
        for (int k = 0; k < 64; ++k) {
            int kk = h * 64 + k;
            float4 wv = *(const float4*)&wl[k * 64 + tn * 4];
            float xv[4];
#pragma unroll
            for (int i = 0; i < 4; ++i) xv[i] = xl[(tm * 4 + i) * 129 + kk];
#pragma unroll
            for (int i = 0; i < 4; ++i) {
                acc[i][0] = fmaf(xv[i], wv.x, acc[i][0]);
                acc[i][1] = fmaf(xv[i], wv.y, acc[i][1]);
                acc[i][2] = fmaf(xv[i], wv.z, acc[i][2]);
                acc[i][3] = fmaf(xv[i], wv.w, acc[i][3]);
            }
        }
    }
#pragma unroll
    for (int i = 0; i < 4; ++i) {
        int m = m0 + tm * 4 + i;
        if (m < NN) {
            float ro = r_out[m];
            US4 o = {f2bf(acc[i][0] * ro), f2bf(acc[i][1] * ro),
                     f2bf(acc[i][2] * ro), f2bf(acc[i][3] * ro)};
            *(US4*)&A[(size_t)m * 64 + tn * 4] = o;
        }
    }
}

// C = (relu(G @ W1 + b1) @ W2) * r_out.  G is bf16.  64 nodes/block.
__global__ __launch_bounds__(256) void k_mlp(const unsigned short* __restrict__ G,
                                             const float* __restrict__ W1,
                                             const float* __restrict__ b1,
                                             const float* __restrict__ W2,
                                             const float* __restrict__ r_out,
                                             float* __restrict__ C) {
    __shared__ float gl[64 * 65];
    __shared__ float w1l[64 * 64];
    __shared__ float w2l[64 * 16];
    int tid = threadIdx.x;
    int m0 = blockIdx.x * 64;
#pragma unroll
    for (int i = 0; i < 2; ++i) {
        int idx = i * 256 + tid;  // 512 chunks of 8 bf16
        int m = idx >> 3, c8 = idx & 7;
        int gm = min(m0 + m, NN - 1);
        uint4 u = *(const uint4*)&G[(size_t)gm * 64 + c8 * 8];
        float* p = &gl[m * 65 + c8 * 8];
        p[0] = bfu(u.x & 0xffffu); p[1] = bfu(u.x >> 16);
        p[2] = bfu(u.y & 0xffffu); p[3] = bfu(u.y >> 16);
        p[4] = bfu(u.z & 0xffffu); p[5] = bfu(u.z >> 16);
        p[6] = bfu(u.w & 0xffffu); p[7] = bfu(u.w >> 16);
    }
    float4* w1l4 = (float4*)w1l;
    const float4* W1_4 = (const float4*)W1;
#pragma unroll
    for (int i = 0; i < 4; ++i) w1l4[i * 256 + tid] = W1_4[i * 256 + tid];
    ((float4*)w2l)[tid] = ((const float4*)W2)[tid];
    __syncthreads();
    int tn = tid & 15, tm = tid >> 4;
    float acc[4][4] = {};
#pragma unroll 4
    for (int k = 0; k < 64; ++k) {
        float4 wv = *(const float4*)&w1l[k * 64 + tn * 4];
        float xv[4];
#pragma unroll
        for (int i = 0; i < 4; ++i) xv[i] = gl[(tm * 4 + i) * 65 + k];
#pragma unroll
        for (int i = 0; i < 4; ++i) {
            acc[i][0] = fmaf(xv[i], wv.x, acc[i][0]);
            acc[i][1] = fmaf(xv[i], wv.y, acc[i][1]);
            acc[i][2] = fmaf(xv[i], wv.z, acc[i][2]);
            acc[i][3] = fmaf(xv[i], wv.w, acc[i][3]);
        }
    }
    float4 bb = *(const float4*)&b1[tn * 4];
    __syncthreads();
#pragma unroll
    for (int i = 0; i < 4; ++i) {
        gl[(tm * 4 + i) * 65 + tn * 4 + 0] = fmaxf(acc[i][0] + bb.x, 0.f);
        gl[(tm * 4 + i) * 65 + tn * 4 + 1] = fmaxf(acc[i][1] + bb.y, 0.f);
        gl[(tm * 4 + i) * 65 + tn * 4 + 2] = fmaxf(acc[i][2] + bb.z, 0.f);
        gl[(tm * 4 + i) * 65 + tn * 4 + 3] = fmaxf(acc[i][3] + bb.w, 0.f);
    }
    __syncthreads();
    int m = tid >> 2, n0 = (tid & 3) * 4;
    float a2[4] = {};
#pragma unroll 8
    for (int k = 0; k < 64; ++k) {
        float zv = gl[m * 65 + k];
        float4 wv = *(const float4*)&w2l[k * 16 + n0];
        a2[0] = fmaf(zv, wv.x, a2[0]);
        a2[1] = fmaf(zv, wv.y, a2[1]);
        a2[2] = fmaf(zv, wv.z, a2[2]);
        a2[3] = fmaf(zv, wv.w, a2[3]);
    }
    int node = m0 + m;
    if (node < NN) {
        float ro = r_out[node];
        float4 o = {a2[0] * ro, a2[1] * ro, a2[2] * ro, a2[3] * ro};
        *(float4*)&C[(size_t)node * 16 + n0] = o;
    }
}

// ---------------- gathers (register-accumulate, per-node wave) ----------------

// d=64 bf16 gather, 1 node/wave, 16 edges in flight (4 groups x 4-deep ILP).
// MODE 0: o16 = bf16(relu(agg*r_in + bias)*r_out)   (layer0 -> B)
// MODE 1: o16 = bf16(agg*r_in)                      (layer1 -> G, feeds k_mlp)
template <int MODE>
__global__ __launch_bounds__(256) void k_gather64(const int* __restrict__ row_start,
                                                  const int* __restrict__ csr,
                                                  const unsigned short* __restrict__ h,
                                                  const float* __restrict__ r_in,
                                                  const float* __restrict__ r_out,
                                                  const float* __restrict__ bias,
                                                  unsigned short* __restrict__ o16) {
    int tid = threadIdx.x;
    int wave = tid >> 6, lane = tid & 63;
    int n = blockIdx.x * 4 + wave;
    int jb = row_start[n], je = row_start[n + 1];
    int g = lane >> 4, f = lane & 15;
    float4 a0 = {0, 0, 0, 0}, a1 = {0, 0, 0, 0};
    float4 a2 = {0, 0, 0, 0}, a3 = {0, 0, 0, 0};
    for (int j = jb; j < je; j += 16) {
        int i0 = j + g, i1 = i0 + 4, i2 = i0 + 8, i3 = i0 + 12;
        int s0 = csr[min(i0, je - 1)];
        int s1 = csr[min(i1, je - 1)];
        int s2 = csr[min(i2, je - 1)];
        int s3 = csr[min(i3, je - 1)];
        uint2 u0 = *(const uint2*)(h + (size_t)s0 * 64 + f * 4);
        uint2 u1 = *(const uint2*)(h + (size_t)s1 * 64 + f * 4);
        uint2 u2 = *(const uint2*)(h + (size_t)s2 * 64 + f * 4);
        uint2 u3 = *(const uint2*)(h + (size_t)s3 * 64 + f * 4);
        float w0 = (i0 < je) ? 1.f : 0.f;
        float w1 = (i1 < je) ? 1.f : 0.f;
        float w2 = (i2 < je) ? 1.f : 0.f;
        float w3 = (i3 < je) ? 1.f : 0.f;
        a0.x = fmaf(w0, bfu(u0.x & 0xffffu), a0.x);
        a0.y = fmaf(w0, bfu(u0.x >> 16), a0.y);
        a0.z = fmaf(w0, bfu(u0.y & 0xffffu), a0.z);
        a0.w = fmaf(w0, bfu(u0.y >> 16), a0.w);
        a1.x = fmaf(w1, bfu(u1.x & 0xffffu), a1.x);
        a1.y = fmaf(w1, bfu(u1.x >> 16), a1.y);
        a1.z = fmaf(w1, bfu(u1.y & 0xffffu), a1.z);
        a1.w = fmaf(w1, bfu(u1.y >> 16), a1.w);
        a2.x = fmaf(w2, bfu(u2.x & 0xffffu), a2.x);
        a2.y = fmaf(w2, bfu(u2.x >> 16), a2.y);
        a2.z = fmaf(w2, bfu(u2.y & 0xffffu), a2.z);
        a2.w = fmaf(w2, bfu(u2.y >> 16), a2.w);
        a3.x = fmaf(w3, bfu(u3.x & 0xffffu), a3.x);
        a3.y = fmaf(w3, bfu(u3.x >> 16), a3.y);
        a3.z = fmaf(w3, bfu(u3.y & 0xffffu), a3.z);
        a3.w = fmaf(w3, bfu(u3.y >> 16), a3.w);
    }
    a0.x += a1.x; a0.y += a1.y; a0.z += a1.z; a0.w += a1.w;
    a2.x += a3.x; a2.y += a3.y; a2.z += a3.z; a2.w += a3.w;
    a0.x += a2.x; a0.y += a2.y; a0.z += a2.z; a0.w += a2.w;
    a0.x += __shfl_xor(a0.x, 16); a0.y += __shfl_xor(a0.y, 16);
    a0.z += __shfl_xor(a0.z, 16); a0.w += __shfl_xor(a0.w, 16);
    a0.x += __shfl_xor(a0.x, 32); a0.y += __shfl_xor(a0.y, 32);
    a0.z += __shfl_xor(a0.z, 32); a0.w += __shfl_xor(a0.w, 32);
    if (g == 0) {
        float ri = r_in[n];
        US4 o;
        if (MODE == 0) {
            float ro = r_out[n];
            float4 bb = *(const float4*)&bias[f * 4];
            o.x = f2bf(fmaxf(fmaf(a0.x, ri, bb.x), 0.f) * ro);
            o.y = f2bf(fmaxf(fmaf(a0.y, ri, bb.y), 0.f) * ro);
            o.z = f2bf(fmaxf(fmaf(a0.z, ri, bb.z), 0.f) * ro);
            o.w = f2bf(fmaxf(fmaf(a0.w, ri, bb.w), 0.f) * ro);
        } else {
            o.x = f2bf(a0.x * ri); o.y = f2bf(a0.y * ri);
            o.z = f2bf(a0.z * ri); o.w = f2bf(a0.w * ri);
        }
        *(US4*)&o16[(size_t)n * 64 + f * 4] = o;
    }
}

// d=16 fp32 gather: out = agg*r_in + b2
__global__ __launch_bounds__(256) void k_gather16(const int* __restrict__ row_start,
                                                  const int* __restrict__ csr,
                                                  const float* __restrict__ C,
                                                  const float* __restrict__ r_in,
                                                  const float* __restrict__ b2,
                                                  float* __restrict__ out) {
    int tid = threadIdx.x;
    int wave = tid >> 6, lane = tid & 63;
    int n = blockIdx.x * 4 + wave;
    int jb = row_start[n], je = row_start[n + 1];
    int g = lane >> 2, f = lane & 3;
    float4 acc = {0, 0, 0, 0};
    for (int j = jb; j < je; j += 16) {
        int i0 = j + g;
        int s = csr[min(i0, je - 1)];
        float4 v = *(const float4*)&C[(size_t)s * 16 + f * 4];
        float w = (i0 < je) ? 1.f : 0.f;
        acc.x = fmaf(w, v.x, acc.x); acc.y = fmaf(w, v.y, acc.y);
        acc.z = fmaf(w, v.z, acc.z); acc.w = fmaf(w, v.w, acc.w);
    }
#pragma unroll
    for (int m = 4; m <= 32; m <<= 1) {
        acc.x += __shfl_xor(acc.x, m); acc.y += __shfl_xor(acc.y, m);
        acc.z += __shfl_xor(acc.z, m); acc.w += __shfl_xor(acc.w, m);
    }
    if (g == 0) {
        float ri = r_in[n];
        float4 bb = *(const float4*)&b2[f * 4];
        float4 o;
        o.x = fmaf(acc.x, ri, bb.x); o.y = fmaf(acc.y, ri, bb.y);
        o.z = fmaf(acc.z, ri, bb.z); o.w = fmaf(acc.w, ri, bb.w);
        *(float4*)&out[(size_t)n * 16 + f * 4] = o;
    }
}

extern "C" void kernel_launch(void* const* d_in, const int* in_sizes, int n_in,
                              void* d_out, int out_size, void* d_ws, size_t ws_size,
                              hipStream_t stream) {
    const float* feats = (const float*)d_in[0];
    const int* src = (const int*)d_in[1];
    const int* dst = (const int*)d_in[2];
    const float* W0 = (const float*)d_in[3];
    const float* b0 = (const float*)d_in[4];
    const float* W1 = (const float*)d_in[5];
    const float* b1 = (const float*)d_in[6];
    const float* W2 = (const float*)d_in[7];
    const float* b2 = (const float*)d_in[8];
    float* out = (float*)d_out;

    // ws (4B units):
    //   r_out[NN] | r_in[NN] | row_start[NN+16] | csr[NE] | E2s[NE] |
    //   R1[32NN] (E2d[NE] then A[bf16] then G[bf16]) | R2[32NN] (B bf16) |
    //   C[16NN] | base_d[NBUCK+1] cursor_d[NBUCK] base_s[NBUCK+1] cursor_s[NBUCK]
    //   bcnt8_d[8*NBUCK] bcnt8_s[8*NBUCK]
    float* ws = (float*)d_ws;
    float* r_out = ws;
    float* r_in = ws + NN;
    int* row_start = (int*)(ws + 2 * NN);
    int* csr = (int*)(ws + 3 * NN + 16);
    int* E2s = (int*)(ws + 3 * NN + 16 + NE);
    float* R1 = ws + 3 * NN + 16 + 2 * (size_t)NE;
    float* R2 = R1 + (size_t)32 * NN;
    float* C = R2 + (size_t)32 * NN;
    int* base_d = (int*)(C + (size_t)16 * NN);  // NBUCK+1
    int* cursor_d = base_d + NBUCK + 1;
    int* base_s = cursor_d + NBUCK;             // NBUCK+1
    int* cursor_s = base_s + NBUCK + 1;
    int* bcnt8_d = cursor_s + NBUCK;            // 8*NBUCK
    int* bcnt8_s = bcnt8_d + NREP * NBUCK;      // 8*NBUCK

    int* E2d = (int*)R1;
    unsigned short* A = (unsigned short*)R1;  // after bcsr (E2d dead)
    unsigned short* G = A;                    // after gather<0> (A dead)
    unsigned short* B = (unsigned short*)R2;

    // build (no per-node scatter atomics anywhere)
    hipMemsetAsync(bcnt8_d, 0, 2 * NREP * NBUCK * sizeof(int), stream);
    k_hist<<<HISTB, 256, 0, stream>>>(src, dst, bcnt8_d, bcnt8_s);
    k_bscan<<<2, 1024, 0, stream>>>(bcnt8_d, bcnt8_s, base_d, cursor_d, base_s, cursor_s);
    k_pairs<<<(NE + PCHUNK - 1) / PCHUNK, 256, 0, stream>>>(src, dst, cursor_d, cursor_s,
                                                            E2d, E2s);
    k_socnt<<<NBUCK, 256, 0, stream>>>(E2s, base_s, r_out);
    k_bcsr<<<NBUCK, 256, 0, stream>>>(E2d, base_d, row_start, r_in, csr);

    // layer 0
    k_gemm0<<<(NN + 63) / 64, 256, 0, stream>>>(feats, W0, r_out, A);
    k_gather64<0><<<NN / 4, 256, 0, stream>>>(row_start, csr, A, r_in, r_out, b0, B);

    // layer 1 (+ layer2 pre-GEMM)
    k_gather64<1><<<NN / 4, 256, 0, stream>>>(row_start, csr, B, r_in, r_out, b0, G);
    k_mlp<<<(NN + 63) / 64, 256, 0, stream>>>(G, W1, b1, W2, r_out, C);

    // layer 2
    k_gather16<<<NN / 4, 256, 0, stream>>>(row_start, csr, C, r_in, b2, out);
}

// Round 10
// 352.559 us; speedup vs baseline: 1.1572x; 1.0197x over previous
//
#include <hip/hip_runtime.h>

#define NN 100000
#define NE 1600000
#define NBUCK 782   // ceil(NN/128), bucket = node >> 7
#define PCHUNK 4096 // edges per k_pairs block -> 391 blocks
#define HISTB 256   // k_hist grid
#define NREP 8      // replicated bucket-count copies

struct alignas(8) US4 { unsigned short x, y, z, w; };

__device__ __forceinline__ float bfu(unsigned int hw) { return __uint_as_float(hw << 16); }
__device__ __forceinline__ unsigned short f2bf(float f) {
    unsigned int u = __float_as_uint(f);
    return (unsigned short)((u + 0x7fffu + ((u >> 16) & 1u)) >> 16);
}

// ---------------- build: dual bucket-ordered edge arrays ----------------

// LDS-only dual histogram (dst buckets + src buckets), replicated global merge.
__global__ __launch_bounds__(256) void k_hist(const int* __restrict__ src,
                                              const int* __restrict__ dst,
                                              int* __restrict__ bcnt8_d,
                                              int* __restrict__ bcnt8_s) {
    __shared__ int hd[NBUCK], hs[NBUCK];
    int tid = threadIdx.x;
    for (int i = tid; i < NBUCK; i += 256) { hd[i] = 0; hs[i] = 0; }
    __syncthreads();
    int* md = bcnt8_d + (size_t)(blockIdx.x & (NREP - 1)) * NBUCK;
    int* ms = bcnt8_s + (size_t)(blockIdx.x & (NREP - 1)) * NBUCK;
    int stride = gridDim.x * 256;
    for (int e = blockIdx.x * 256 + tid; e < NE; e += stride) {
        atomicAdd(&hd[dst[e] >> 7], 1);
        atomicAdd(&hs[src[e] >> 7], 1);
    }
    __syncthreads();
    for (int i = tid; i < NBUCK; i += 256) {
        if (hd[i]) atomicAdd(&md[i], hd[i]);
        if (hs[i]) atomicAdd(&ms[i], hs[i]);
    }
}

// block 0: scan dst buckets; block 1: scan src buckets
__global__ __launch_bounds__(1024) void k_bscan(const int* __restrict__ bcnt8_d,
                                                const int* __restrict__ bcnt8_s,
                                                int* __restrict__ base_d,
                                                int* __restrict__ cursor_d,
                                                int* __restrict__ base_s,
                                                int* __restrict__ cursor_s) {
    __shared__ int tmp[1024];
    int t = threadIdx.x;
    const int* bc = blockIdx.x ? bcnt8_s : bcnt8_d;
    int* base = blockIdx.x ? base_s : base_d;
    int* cur = blockIdx.x ? cursor_s : cursor_d;
    int v = 0;
    if (t < NBUCK)
#pragma unroll
        for (int c = 0; c < NREP; ++c) v += bc[c * NBUCK + t];
    tmp[t] = v;
    __syncthreads();
    for (int off = 1; off < 1024; off <<= 1) {
        int u = (t >= off) ? tmp[t - off] : 0;
        __syncthreads();
        tmp[t] += u;
        __syncthreads();
    }
    int excl = tmp[t] - v;
    if (t < NBUCK) {
        base[t] = excl;
        cur[t] = excl;
    }
    if (t == 0) base[NBUCK] = NE;
}

// dual LDS-binned scatter: bulk reservation per (block,bucket), packed words
// into per-block contiguous runs.  E2d = (src<<7)|(dst&127); E2s = src&127 (byte).
__global__ __launch_bounds__(256) void k_pairs(const int* __restrict__ src,
                                               const int* __restrict__ dst,
                                               int* __restrict__ cursor_d,
                                               int* __restrict__ cursor_s,
                                               int* __restrict__ E2d,
                                               unsigned char* __restrict__ E2s) {
    __shared__ int hist_d[NBUCK], gbase_d[NBUCK], hist_s[NBUCK], gbase_s[NBUCK];
    int tid = threadIdx.x;
    for (int i = tid; i < NBUCK; i += 256) { hist_d[i] = 0; hist_s[i] = 0; }
    __syncthreads();
    int base = blockIdx.x * PCHUNK;
#pragma unroll
    for (int i = 0; i < PCHUNK / 256; ++i) {
        int e = base + i * 256 + tid;
        if (e < NE) {
            atomicAdd(&hist_d[dst[e] >> 7], 1);
            atomicAdd(&hist_s[src[e] >> 7], 1);
        }
    }
    __syncthreads();
    // rotate reservation start per block to decorrelate cursor-line contention
    int rot = (int)((blockIdx.x * 191u) % NBUCK);
    for (int ii = tid; ii < NBUCK; ii += 256) {
        int i = ii + rot;
        if (i >= NBUCK) i -= NBUCK;
        int h = hist_d[i];
        if (h) gbase_d[i] = atomicAdd(&cursor_d[i], h);
        hist_d[i] = 0;
        h = hist_s[i];
        if (h) gbase_s[i] = atomicAdd(&cursor_s[i], h);
        hist_s[i] = 0;
    }
    __syncthreads();
#pragma unroll
    for (int i = 0; i < PCHUNK / 256; ++i) {
        int e = base + i * 256 + tid;
        if (e < NE) {
            int s = src[e], d = dst[e];
            int bd = d >> 7;
            int pd = atomicAdd(&hist_d[bd], 1);
            E2d[gbase_d[bd] + pd] = (s << 7) | (d & 127);
            int bs = s >> 7;
            int ps = atomicAdd(&hist_s[bs], 1);
            E2s[gbase_s[bs] + ps] = (unsigned char)(s & 127);
        }
    }
}

// merged per-bucket node pass.  b < NBUCK: dst bucket -> row_start, r_in, csr.
// b >= NBUCK: src bucket -> r_out (out-degree rsqrt).
__global__ __launch_bounds__(256) void k_nodes(const int* __restrict__ E2d,
                                               const int* __restrict__ base_d,
                                               const unsigned char* __restrict__ E2s,
                                               const int* __restrict__ base_s,
                                               int* __restrict__ row_start,
                                               float* __restrict__ r_in,
                                               float* __restrict__ r_out,
                                               int* __restrict__ csr) {
    __shared__ int cnt[128], cur[128];
    int tid = threadIdx.x;
    int b = blockIdx.x;
    if (b >= NBUCK) {  // ---- out-degree count ----
        b -= NBUCK;
        int base = base_s[b], end = base_s[b + 1];
        if (tid < 128) cnt[tid] = 0;
        __syncthreads();
        for (int i = base + tid; i < end; i += 256) atomicAdd(&cnt[E2s[i]], 1);
        __syncthreads();
        if (tid < 128) {
            int node = b * 128 + tid;
            if (node < NN) r_out[node] = rsqrtf((float)max(cnt[tid], 1));
        }
        return;
    }
    // ---- per-node CSR within dst bucket ----
    int base = base_d[b], end = base_d[b + 1];
    if (tid < 128) cnt[tid] = 0;
    __syncthreads();
    for (int i = base + tid; i < end; i += 256) atomicAdd(&cnt[E2d[i] & 127], 1);
    __syncthreads();
    int v = (tid < 128) ? cnt[tid] : 0;
    for (int off = 1; off < 128; off <<= 1) {
        int u = (tid >= off && tid < 128) ? cnt[tid - off] : 0;
        __syncthreads();
        if (tid < 128) cnt[tid] += u;
        __syncthreads();
    }
    if (tid < 128) {
        int excl = cnt[tid] - v;  // exclusive scan within bucket
        cur[tid] = excl;
        int node = b * 128 + tid;
        if (node <= NN) row_start[node] = base + excl;
        if (node < NN) r_in[node] = rsqrtf((float)max(v, 1));
    }
    __syncthreads();
    for (int i = base + tid; i < end; i += 256) {
        int e = E2d[i];
        int pos = atomicAdd(&cur[e & 127], 1);
        csr[base + pos] = e >> 7;
    }
}

// ---------------- dense GEMMs ----------------

// A(bf16) = (x @ W0) * r_out.  64 nodes/block, thread = 4m x 4n, K=128 in two halves.
__global__ __launch_bounds__(256) void k_gemm0(const float* __restrict__ x,
                                               const float* __restrict__ W0,
                                               const float* __restrict__ r_out,
                                               unsigned short* __restrict__ A) {
    __shared__ float xl[64 * 129];
    __shared__ float wl[64 * 64];
    int tid = threadIdx.x;
    int m0 = blockIdx.x * 64;
#pragma unroll
    for (int i = 0; i < 8; ++i) {
        int idx = i * 256 + tid;
        int m = idx >> 5, kc = idx & 31;
        int gm = min(m0 + m, NN - 1);
        float4 v = *(const float4*)&x[(size_t)gm * 128 + kc * 4];
        float* p = &xl[m * 129 + kc * 4];
        p[0] = v.x; p[1] = v.y; p[2] = v.z; p[3] = v.w;
    }
    int tn = tid & 15, tm = tid >> 4;
    float acc[4][4] = {};
    const float4* W4 = (const float4*)W0;
    float4* wl4 = (float4*)wl;
    for (int h = 0; h < 2; ++h) {
        __syncthreads();
#pragma unroll
        for (int i = 0; i < 4; ++i) wl4[i * 256 + tid] = W4[h * 1024 + i * 256 + tid];
        __syncthreads();
#pragma unroll 4
        for (int k = 0; k < 64; ++k) {
            int kk = h * 64 + k;
            float4 wv = *(const float4*)&wl[k * 64 + tn * 4];
            float xv[4];
#pragma unroll
            for (int i = 0; i < 4; ++i) xv[i] = xl[(tm * 4 + i) * 129 + kk];
#pragma unroll
            for (int i = 0; i < 4; ++i) {
                acc[i][0] = fmaf(xv[i], wv.x, acc[i][0]);
                acc[i][1] = fmaf(xv[i], wv.y, acc[i][1]);
                acc[i][2] = fmaf(xv[i], wv.z, acc[i][2]);
                acc[i][3] = fmaf(xv[i], wv.w, acc[i][3]);
            }
        }
    }
#pragma unroll
    for (int i = 0; i < 4; ++i) {
        int m = m0 + tm * 4 + i;
        if (m < NN) {
            float ro = r_out[m];
            US4 o = {f2bf(acc[i][0] * ro), f2bf(acc[i][1] * ro),
                     f2bf(acc[i][2] * ro), f2bf(acc[i][3] * ro)};
            *(US4*)&A[(size_t)m * 64 + tn * 4] = o;
        }
    }
}

// C = (relu(G @ W1 + b1) @ W2) * r_out.  G is bf16.  64 nodes/block.
__global__ __launch_bounds__(256) void k_mlp(const unsigned short* __restrict__ G,
                                             const float* __restrict__ W1,
                                             const float* __restrict__ b1,
                                             const float* __restrict__ W2,
                                             const float* __restrict__ r_out,
                                             float* __restrict__ C) {
    __shared__ float gl[64 * 65];
    __shared__ float w1l[64 * 64];
    __shared__ float w2l[64 * 16];
    int tid = threadIdx.x;
    int m0 = blockIdx.x * 64;
#pragma unroll
    for (int i = 0; i < 2; ++i) {
        int idx = i * 256 + tid;  // 512 chunks of 8 bf16
        int m = idx >> 3, c8 = idx & 7;
        int gm = min(m0 + m, NN - 1);
        uint4 u = *(const uint4*)&G[(size_t)gm * 64 + c8 * 8];
        float* p = &gl[m * 65 + c8 * 8];
        p[0] = bfu(u.x & 0xffffu); p[1] = bfu(u.x >> 16);
        p[2] = bfu(u.y & 0xffffu); p[3] = bfu(u.y >> 16);
        p[4] = bfu(u.z & 0xffffu); p[5] = bfu(u.z >> 16);
        p[6] = bfu(u.w & 0xffffu); p[7] = bfu(u.w >> 16);
    }
    float4* w1l4 = (float4*)w1l;
    const float4* W1_4 = (const float4*)W1;
#pragma unroll
    for (int i = 0; i < 4; ++i) w1l4[i * 256 + tid] = W1_4[i * 256 + tid];
    ((float4*)w2l)[tid] = ((const float4*)W2)[tid];
    __syncthreads();
    int tn = tid & 15, tm = tid >> 4;
    float acc[4][4] = {};
#pragma unroll 4
    for (int k = 0; k < 64; ++k) {
        float4 wv = *(const float4*)&w1l[k * 64 + tn * 4];
        float xv[4];
#pragma unroll
        for (int i = 0; i < 4; ++i) xv[i] = gl[(tm * 4 + i) * 65 + k];
#pragma unroll
        for (int i = 0; i < 4; ++i) {
            acc[i][0] = fmaf(xv[i], wv.x, acc[i][0]);
            acc[i][1] = fmaf(xv[i], wv.y, acc[i][1]);
            acc[i][2] = fmaf(xv[i], wv.z, acc[i][2]);
            acc[i][3] = fmaf(xv[i], wv.w, acc[i][3]);
        }
    }
    float4 bb = *(const float4*)&b1[tn * 4];
    __syncthreads();
#pragma unroll
    for (int i = 0; i < 4; ++i) {
        gl[(tm * 4 + i) * 65 + tn * 4 + 0] = fmaxf(acc[i][0] + bb.x, 0.f);
        gl[(tm * 4 + i) * 65 + tn * 4 + 1] = fmaxf(acc[i][1] + bb.y, 0.f);
        gl[(tm * 4 + i) * 65 + tn * 4 + 2] = fmaxf(acc[i][2] + bb.z, 0.f);
        gl[(tm * 4 + i) * 65 + tn * 4 + 3] = fmaxf(acc[i][3] + bb.w, 0.f);
    }
    __syncthreads();
    int m = tid >> 2, n0 = (tid & 3) * 4;
    float a2[4] = {};
#pragma unroll 8
    for (int k = 0; k < 64; ++k) {
        float zv = gl[m * 65 + k];
        float4 wv = *(const float4*)&w2l[k * 16 + n0];
        a2[0] = fmaf(zv, wv.x, a2[0]);
        a2[1] = fmaf(zv, wv.y, a2[1]);
        a2[2] = fmaf(zv, wv.z, a2[2]);
        a2[3] = fmaf(zv, wv.w, a2[3]);
    }
    int node = m0 + m;
    if (node < NN) {
        float ro = r_out[node];
        float4 o = {a2[0] * ro, a2[1] * ro, a2[2] * ro, a2[3] * ro};
        *(float4*)&C[(size_t)node * 16 + n0] = o;
    }
}

// ---------------- gathers (register-accumulate, per-node wave) ----------------

// d=64 bf16 gather, 1 node/wave, 16 edges in flight (4 groups x 4-deep ILP).
// MODE 0: o16 = bf16(relu(agg*r_in + bias)*r_out)   (layer0 -> B)
// MODE 1: o16 = bf16(agg*r_in)                      (layer1 -> G, feeds k_mlp)
template <int MODE>
__global__ __launch_bounds__(256) void k_gather64(const int* __restrict__ row_start,
                                                  const int* __restrict__ csr,
                                                  const unsigned short* __restrict__ h,
                                                  const float* __restrict__ r_in,
                                                  const float* __restrict__ r_out,
                                                  const float* __restrict__ bias,
                                                  unsigned short* __restrict__ o16) {
    int tid = threadIdx.x;
    int wave = tid >> 6, lane = tid & 63;
    int n = blockIdx.x * 4 + wave;
    int jb = row_start[n], je = row_start[n + 1];
    int g = lane >> 4, f = lane & 15;
    float4 a0 = {0, 0, 0, 0}, a1 = {0, 0, 0, 0};
    float4 a2 = {0, 0, 0, 0}, a3 = {0, 0, 0, 0};
    for (int j = jb; j < je; j += 16) {
        int i0 = j + g, i1 = i0 + 4, i2 = i0 + 8, i3 = i0 + 12;
        int s0 = csr[min(i0, je - 1)];
        int s1 = csr[min(i1, je - 1)];
        int s2 = csr[min(i2, je - 1)];
        int s3 = csr[min(i3, je - 1)];
        uint2 u0 = *(const uint2*)(h + (size_t)s0 * 64 + f * 4);
        uint2 u1 = *(const uint2*)(h + (size_t)s1 * 64 + f * 4);
        uint2 u2 = *(const uint2*)(h + (size_t)s2 * 64 + f * 4);
        uint2 u3 = *(const uint2*)(h + (size_t)s3 * 64 + f * 4);
        float w0 = (i0 < je) ? 1.f : 0.f;
        float w1 = (i1 < je) ? 1.f : 0.f;
        float w2 = (i2 < je) ? 1.f : 0.f;
        float w3 = (i3 < je) ? 1.f : 0.f;
        a0.x = fmaf(w0, bfu(u0.x & 0xffffu), a0.x);
        a0.y = fmaf(w0, bfu(u0.x >> 16), a0.y);
        a0.z = fmaf(w0, bfu(u0.y & 0xffffu), a0.z);
        a0.w = fmaf(w0, bfu(u0.y >> 16), a0.w);
        a1.x = fmaf(w1, bfu(u1.x & 0xffffu), a1.x);
        a1.y = fmaf(w1, bfu(u1.x >> 16), a1.y);
        a1.z = fmaf(w1, bfu(u1.y & 0xffffu), a1.z);
        a1.w = fmaf(w1, bfu(u1.y >> 16), a1.w);
        a2.x = fmaf(w2, bfu(u2.x & 0xffffu), a2.x);
        a2.y = fmaf(w2, bfu(u2.x >> 16), a2.y);
        a2.z = fmaf(w2, bfu(u2.y & 0xffffu), a2.z);
        a2.w = fmaf(w2, bfu(u2.y >> 16), a2.w);
        a3.x = fmaf(w3, bfu(u3.x & 0xffffu), a3.x);
        a3.y = fmaf(w3, bfu(u3.x >> 16), a3.y);
        a3.z = fmaf(w3, bfu(u3.y & 0xffffu), a3.z);
        a3.w = fmaf(w3, bfu(u3.y >> 16), a3.w);
    }
    a0.x += a1.x; a0.y += a1.y; a0.z += a1.z; a0.w += a1.w;
    a2.x += a3.x; a2.y += a3.y; a2.z += a3.z; a2.w += a3.w;
    a0.x += a2.x; a0.y += a2.y; a0.z += a2.z; a0.w += a2.w;
    a0.x += __shfl_xor(a0.x, 16); a0.y += __shfl_xor(a0.y, 16);
    a0.z += __shfl_xor(a0.z, 16); a0.w += __shfl_xor(a0.w, 16);
    a0.x += __shfl_xor(a0.x, 32); a0.y += __shfl_xor(a0.y, 32);
    a0.z += __shfl_xor(a0.z, 32); a0.w += __shfl_xor(a0.w, 32);
    if (g == 0) {
        float ri = r_in[n];
        US4 o;
        if (MODE == 0) {
            float ro = r_out[n];
            float4 bb = *(const float4*)&bias[f * 4];
            o.x = f2bf(fmaxf(fmaf(a0.x, ri, bb.x), 0.f) * ro);
            o.y = f2bf(fmaxf(fmaf(a0.y, ri, bb.y), 0.f) * ro);
            o.z = f2bf(fmaxf(fmaf(a0.z, ri, bb.z), 0.f) * ro);
            o.w = f2bf(fmaxf(fmaf(a0.w, ri, bb.w), 0.f) * ro);
        } else {
            o.x = f2bf(a0.x * ri); o.y = f2bf(a0.y * ri);
            o.z = f2bf(a0.z * ri); o.w = f2bf(a0.w * ri);
        }
        *(US4*)&o16[(size_t)n * 64 + f * 4] = o;
    }
}

// d=16 fp32 gather: out = agg*r_in + b2
__global__ __launch_bounds__(256) void k_gather16(const int* __restrict__ row_start,
                                                  const int* __restrict__ csr,
                                                  const float* __restrict__ C,
                                                  const float* __restrict__ r_in,
                                                  const float* __restrict__ b2,
                                                  float* __restrict__ out) {
    int tid = threadIdx.x;
    int wave = tid >> 6, lane = tid & 63;
    int n = blockIdx.x * 4 + wave;
    int jb = row_start[n], je = row_start[n + 1];
    int g = lane >> 2, f = lane & 3;
    float4 acc = {0, 0, 0, 0};
    for (int j = jb; j < je; j += 16) {
        int i0 = j + g;
        int s = csr[min(i0, je - 1)];
        float4 v = *(const float4*)&C[(size_t)s * 16 + f * 4];
        float w = (i0 < je) ? 1.f : 0.f;
        acc.x = fmaf(w, v.x, acc.x); acc.y = fmaf(w, v.y, acc.y);
        acc.z = fmaf(w, v.z, acc.z); acc.w = fmaf(w, v.w, acc.w);
    }
#pragma unroll
    for (int m = 4; m <= 32; m <<= 1) {
        acc.x += __shfl_xor(acc.x, m); acc.y += __shfl_xor(acc.y, m);
        acc.z += __shfl_xor(acc.z, m); acc.w += __shfl_xor(acc.w, m);
    }
    if (g == 0) {
        float ri = r_in[n];
        float4 bb = *(const float4*)&b2[f * 4];
        float4 o;
        o.x = fmaf(acc.x, ri, bb.x); o.y = fmaf(acc.y, ri, bb.y);
        o.z = fmaf(acc.z, ri, bb.z); o.w = fmaf(acc.w, ri, bb.w);
        *(float4*)&out[(size_t)n * 16 + f * 4] = o;
    }
}

extern "C" void kernel_launch(void* const* d_in, const int* in_sizes, int n_in,
                              void* d_out, int out_size, void* d_ws, size_t ws_size,
                              hipStream_t stream) {
    const float* feats = (const float*)d_in[0];
    const int* src = (const int*)d_in[1];
    const int* dst = (const int*)d_in[2];
    const float* W0 = (const float*)d_in[3];
    const float* b0 = (const float*)d_in[4];
    const float* W1 = (const float*)d_in[5];
    const float* b1 = (const float*)d_in[6];
    const float* W2 = (const float*)d_in[7];
    const float* b2 = (const float*)d_in[8];
    float* out = (float*)d_out;

    // ws (4B units):
    //   r_out[NN] | r_in[NN] | row_start[NN+16] | csr[NE] | E2s[NE bytes = NE/4] |
    //   R1[32NN] (E2d[NE] then A[bf16] then G[bf16]) | R2[32NN] (B bf16) |
    //   C[16NN] | base_d[NBUCK+1] cursor_d[NBUCK] base_s[NBUCK+1] cursor_s[NBUCK]
    //   bcnt8_d[8*NBUCK] bcnt8_s[8*NBUCK]
    float* ws = (float*)d_ws;
    float* r_out = ws;
    float* r_in = ws + NN;
    int* row_start = (int*)(ws + 2 * NN);
    int* csr = (int*)(ws + 3 * NN + 16);
    unsigned char* E2s = (unsigned char*)(ws + 3 * NN + 16 + NE);
    float* R1 = ws + 3 * NN + 16 + NE + NE / 4;
    float* R2 = R1 + (size_t)32 * NN;
    float* C = R2 + (size_t)32 * NN;
    int* base_d = (int*)(C + (size_t)16 * NN);  // NBUCK+1
    int* cursor_d = base_d + NBUCK + 1;
    int* base_s = cursor_d + NBUCK;             // NBUCK+1
    int* cursor_s = base_s + NBUCK + 1;
    int* bcnt8_d = cursor_s + NBUCK;            // 8*NBUCK
    int* bcnt8_s = bcnt8_d + NREP * NBUCK;      // 8*NBUCK

    int* E2d = (int*)R1;
    unsigned short* A = (unsigned short*)R1;  // after k_nodes (E2d dead)
    unsigned short* G = A;                    // after gather<0> (A dead)
    unsigned short* B = (unsigned short*)R2;

    // build (no per-node scatter atomics anywhere)
    hipMemsetAsync(bcnt8_d, 0, 2 * NREP * NBUCK * sizeof(int), stream);
    k_hist<<<HISTB, 256, 0, stream>>>(src, dst, bcnt8_d, bcnt8_s);
    k_bscan<<<2, 1024, 0, stream>>>(bcnt8_d, bcnt8_s, base_d, cursor_d, base_s, cursor_s);
    k_pairs<<<(NE + PCHUNK - 1) / PCHUNK, 256, 0, stream>>>(src, dst, cursor_d, cursor_s,
                                                            E2d, E2s);
    k_nodes<<<2 * NBUCK, 256, 0, stream>>>(E2d, base_d, E2s, base_s,
                                           row_start, r_in, r_out, csr);

    // layer 0
    k_gemm0<<<(NN + 63) / 64, 256, 0, stream>>>(feats, W0, r_out, A);
    k_gather64<0><<<NN / 4, 256, 0, stream>>>(row_start, csr, A, r_in, r_out, b0, B);

    // layer 1 (+ layer2 pre-GEMM)
    k_gather64<1><<<NN / 4, 256, 0, stream>>>(row_start, csr, B, r_in, r_out, b0, G);
    k_mlp<<<(NN + 63) / 64, 256, 0, stream>>>(G, W1, b1, W2, r_out, C);

    // layer 2
    k_gather16<<<NN / 4, 256, 0, stream>>>(row_start, csr, C, r_in, b2, out);
}